// Round 5
// baseline (196.715 us; speedup 1.0000x reference)
//
#include <hip/hip_runtime.h>
#include <math.h>

#define B 8
#define S 128
#define D 256
#define H 8
#define T 129
#define HD 32
#define NEG_INF -1000000000.0f
#define LN_EPS 1e-5f

// ---------------------------------------------------------------------------
// Kernel 1: ALL pre-attention work. blockIdx.x slabs:
//   [0,258)   : v  = nv @ Wv + bv       (1032 rows, row-major)
//   [258,514) : U  = desc @ We1_top+be1 (1024 rows, row-major + transposed Ut)
//   [514,770) : Vt = (desc @ We1_bot)^T (transposed only)
//   [770,835) : qdkd = nv @ fold(Wq,Wk,wa)+fold(bq,bk)  (1032 x 16)
//   835       : W2ca[c*8+h] = We2[c,h*32+:].wa_e ; econst[h]
// Dense slabs: 4 rows x 256 cols, thread = 1 col, X via wave-uniform float4
// loads (scalarizes to s_load; no LDS, no barrier), W prefetched 1 chunk.
// ---------------------------------------------------------------------------
__global__ __launch_bounds__(256) void gemm_all(
    const float* __restrict__ nv, const float* __restrict__ desc,
    const float* __restrict__ Wq, const float* __restrict__ bq,
    const float* __restrict__ Wk, const float* __restrict__ bk,
    const float* __restrict__ Wv, const float* __restrict__ bv,
    const float* __restrict__ We1, const float* __restrict__ be1,
    const float* __restrict__ We2, const float* __restrict__ be2,
    const float* __restrict__ wa,
    float* __restrict__ v, float* __restrict__ U, float* __restrict__ Ut,
    float* __restrict__ Vt, float* __restrict__ qdkd,
    float* __restrict__ W2ca, float* __restrict__ econst)
{
    const int blk = blockIdx.x;
    const int tid = threadIdx.x;

    __shared__ float xs16[16 * 260];
    __shared__ float wq_s[4096];
    __shared__ float bq_s[16];

    if (blk < 770) {
        // ---------------- dense 4x256 GEMM slabs ----------------
        const float* X; const float* W; const float* bias; int r0; int mode;
        if (blk < 258)      { X = nv;   W = Wv;        bias = bv;      r0 = blk * 4;         mode = 0; }
        else if (blk < 514) { X = desc; W = We1;       bias = be1;     r0 = (blk - 258) * 4; mode = 1; }
        else                { X = desc; W = We1 + D*D; bias = nullptr; r0 = (blk - 514) * 4; mode = 2; }
        const int c = tid;

        const float* x0 = X + (r0 + 0) * D;
        const float* x1 = X + (r0 + 1) * D;
        const float* x2 = X + (r0 + 2) * D;
        const float* x3 = X + (r0 + 3) * D;

        float acc0 = 0.f, acc1 = 0.f, acc2 = 0.f, acc3 = 0.f;
        float w[8], nw[8];
        #pragma unroll
        for (int q = 0; q < 8; ++q) w[q] = W[q * D + c];

        for (int kk = 0; kk < 256; kk += 8) {
            const int kn = kk + 8;
            if (kn < 256) {
                #pragma unroll
                for (int q = 0; q < 8; ++q) nw[q] = W[(kn + q) * D + c];
            }
            float xv0[8], xv1[8], xv2[8], xv3[8];
            *(float4*)&xv0[0] = *(const float4*)(x0 + kk);
            *(float4*)&xv0[4] = *(const float4*)(x0 + kk + 4);
            *(float4*)&xv1[0] = *(const float4*)(x1 + kk);
            *(float4*)&xv1[4] = *(const float4*)(x1 + kk + 4);
            *(float4*)&xv2[0] = *(const float4*)(x2 + kk);
            *(float4*)&xv2[4] = *(const float4*)(x2 + kk + 4);
            *(float4*)&xv3[0] = *(const float4*)(x3 + kk);
            *(float4*)&xv3[4] = *(const float4*)(x3 + kk + 4);
            #pragma unroll
            for (int q = 0; q < 8; ++q) {
                acc0 = fmaf(xv0[q], w[q], acc0);
                acc1 = fmaf(xv1[q], w[q], acc1);
                acc2 = fmaf(xv2[q], w[q], acc2);
                acc3 = fmaf(xv3[q], w[q], acc3);
            }
            if (kn < 256) {
                #pragma unroll
                for (int q = 0; q < 8; ++q) w[q] = nw[q];
            }
        }

        const float bb = bias ? bias[c] : 0.f;
        const float o0 = acc0 + bb, o1 = acc1 + bb, o2 = acc2 + bb, o3 = acc3 + bb;

        if (mode == 0) {
            v[(r0 + 0) * D + c] = o0;
            v[(r0 + 1) * D + c] = o1;
            v[(r0 + 2) * D + c] = o2;
            v[(r0 + 3) * D + c] = o3;
        } else {
            const int b_ = r0 >> 7, rl = r0 & 127;
            float4 tv; tv.x = o0; tv.y = o1; tv.z = o2; tv.w = o3;
            if (mode == 1) {
                U[(r0 + 0) * D + c] = o0;
                U[(r0 + 1) * D + c] = o1;
                U[(r0 + 2) * D + c] = o2;
                U[(r0 + 3) * D + c] = o3;
                *(float4*)&Ut[(b_ * D + c) * S + rl] = tv;
            } else {
                *(float4*)&Vt[(b_ * D + c) * S + rl] = tv;
            }
        }
    } else if (blk < 835) {
        // ---------------- qdkd slab (self-folding, LDS) ----------------
        const int r0 = (blk - 770) * 16;

        for (int t = tid; t < 4096; t += 256) {
            const int k = t >> 4, cc = t & 15;
            const float* Wsrc = (cc < 8) ? Wq : Wk;
            const float* wap  = (cc < 8) ? wa : wa + HD;
            const int h = cc & 7;
            float s = 0.f;
            #pragma unroll
            for (int d = 0; d < HD; ++d) s = fmaf(Wsrc[k*D + h*HD + d], wap[d], s);
            wq_s[t] = s;
        }
        if (tid < 16) {
            const float* bsrc = (tid < 8) ? bq : bk;
            const float* wap  = (tid < 8) ? wa : wa + HD;
            const int h = tid & 7;
            float s = 0.f;
            #pragma unroll
            for (int d = 0; d < HD; ++d) s = fmaf(bsrc[h*HD + d], wap[d], s);
            bq_s[tid] = s;
        }
        for (int t = tid; t < 16 * 256; t += 256) {
            const int r = t >> 8, cch = t & 255, rr = r0 + r;
            xs16[r * 260 + cch] = (rr < B*T) ? nv[rr * D + cch] : 0.f;
        }
        __syncthreads();

        const int r = tid >> 4, cc = tid & 15;
        float acc = 0.f;
        for (int kk = 0; kk < 256; kk += 4) {
            const float4 x = *(const float4*)&xs16[r * 260 + kk];
            acc = fmaf(x.x, wq_s[(kk+0)*16 + cc], acc);
            acc = fmaf(x.y, wq_s[(kk+1)*16 + cc], acc);
            acc = fmaf(x.z, wq_s[(kk+2)*16 + cc], acc);
            acc = fmaf(x.w, wq_s[(kk+3)*16 + cc], acc);
        }
        const int rr = r0 + r;
        if (rr < B*T) qdkd[rr * 16 + cc] = acc + bq_s[cc];
    } else {
        // ---------------- W2ca fold + econst ----------------
        for (int t = tid; t < 2048; t += 256) {
            const int cch = t >> 3, h = t & 7;
            float s = 0.f;
            #pragma unroll
            for (int d = 0; d < HD; ++d) s = fmaf(We2[cch*D + h*HD + d], wa[2*HD + d], s);
            W2ca[t] = s;
        }
        if (tid < 8) {
            float s = 0.f;
            #pragma unroll
            for (int d = 0; d < HD; ++d) s = fmaf(be2[tid*HD + d], wa[2*HD + d], s);
            econst[tid] = s;
        }
    }
}

// ---------------------------------------------------------------------------
// Kernel 2 (v3): lane-per-edge. Block = (b*T + i), 512 thr = 8 waves.
// wave wid: jh = wid&1 (lane covers j = jh*64+lane, 0-based), cc = wid>>1
// (channels [cc*64, cc*64+64)).
//  Pass 1: per-lane LN stats over 64-ch chunk -> LDS -> combine (barrier).
//  Pass 2: t = relu((y-mu)*rs*g+b); acc_h += t*w2[c][h]  (no cross-lane ops).
//  Phase B: wave = head softmax (+prior bias via __logf).
//  Phase C: ctx = attn @ v.
// Channel-uniform operands (urow, g, b, W2ca) are wave-uniform global reads.
// ---------------------------------------------------------------------------
__global__ __launch_bounds__(512) void edge_attn(
    const float* __restrict__ U, const float* __restrict__ Ut,
    const float* __restrict__ Vt,
    const float* __restrict__ W2ca, const float* __restrict__ econst,
    const float* __restrict__ ln_g, const float* __restrict__ ln_b,
    const float* __restrict__ qdkd, const float* __restrict__ prior,
    const float* __restrict__ v, const float* __restrict__ ba,
    float* __restrict__ out_basis, float* __restrict__ out_attn)
{
    const int bid = blockIdx.x;
    const int b = bid / T, i = bid % T;
    const int tid = threadIdx.x, lane = tid & 63, wid = tid >> 6;
    const int jh = wid & 1, cc = wid >> 1;
    const int j = jh * 64 + lane;          // 0..127
    const int cbase = cc * 64;

    __shared__ float s1a[4][128], s2a[4][128];
    __shared__ float part[4][8][128];
    __shared__ float pat[8][128];

    const float* vtb  = Vt + (size_t)b * D * S;
    const float* utb  = Ut + (size_t)b * D * S;
    const float* urow = U + (size_t)(b * S + (i >= 1 ? i - 1 : 0)) * D;

    // ---- Pass 1: LN stats ----
    float s1 = 0.f, s2 = 0.f;
    if (i >= 1) {
        #pragma unroll 4
        for (int c = cbase; c < cbase + 64; c += 4) {
            const float4 u4 = *(const float4*)(urow + c);
            const float v0 = vtb[(c+0)*S + j], v1 = vtb[(c+1)*S + j];
            const float v2 = vtb[(c+2)*S + j], v3 = vtb[(c+3)*S + j];
            const float y0 = u4.x + v0, y1 = u4.y + v1;
            const float y2 = u4.z + v2, y3 = u4.w + v3;
            s1 += y0 + y1 + y2 + y3;
            s2 = fmaf(y0, y0, fmaf(y1, y1, fmaf(y2, y2, fmaf(y3, y3, s2))));
        }
    } else {
        #pragma unroll 4
        for (int c = cbase; c < cbase + 64; c += 4) {
            const float y0 = utb[(c+0)*S + j] + vtb[(c+0)*S + j];
            const float y1 = utb[(c+1)*S + j] + vtb[(c+1)*S + j];
            const float y2 = utb[(c+2)*S + j] + vtb[(c+2)*S + j];
            const float y3 = utb[(c+3)*S + j] + vtb[(c+3)*S + j];
            s1 += y0 + y1 + y2 + y3;
            s2 = fmaf(y0, y0, fmaf(y1, y1, fmaf(y2, y2, fmaf(y3, y3, s2))));
        }
    }
    s1a[cc][j] = s1;
    s2a[cc][j] = s2;
    __syncthreads();

    const float st1 = s1a[0][j] + s1a[1][j] + s1a[2][j] + s1a[3][j];
    const float st2 = s2a[0][j] + s2a[1][j] + s2a[2][j] + s2a[3][j];
    const float mu  = st1 * (1.f / D);
    const float var = st2 * (1.f / D) - mu * mu;
    const float rs  = rsqrtf(var + LN_EPS);

    // ---- Pass 2: normalize + relu + 8-head dot ----
    float a0=0.f,a1=0.f,a2=0.f,a3=0.f,a4=0.f,a5=0.f,a6=0.f,a7=0.f;
    #pragma unroll 4
    for (int c = cbase; c < cbase + 64; ++c) {
        const float u  = (i >= 1) ? urow[c] : utb[c*S + j];
        const float vv = vtb[c*S + j];
        float t = fmaf((u + vv - mu) * rs, ln_g[c], ln_b[c]);
        t = fmaxf(t, 0.f);
        const float4 wA = *(const float4*)(W2ca + c*8);
        const float4 wB = *(const float4*)(W2ca + c*8 + 4);
        a0 = fmaf(t, wA.x, a0); a1 = fmaf(t, wA.y, a1);
        a2 = fmaf(t, wA.z, a2); a3 = fmaf(t, wA.w, a3);
        a4 = fmaf(t, wB.x, a4); a5 = fmaf(t, wB.y, a5);
        a6 = fmaf(t, wB.z, a6); a7 = fmaf(t, wB.w, a7);
    }
    part[cc][0][j] = a0; part[cc][1][j] = a1;
    part[cc][2][j] = a2; part[cc][3][j] = a3;
    part[cc][4][j] = a4; part[cc][5][j] = a5;
    part[cc][6][j] = a6; part[cc][7][j] = a7;
    __syncthreads();

    // ---- Phase B: softmax (wave = head) ----
    const int h = wid;
    const float ecw = econst[h];
    const float ba0 = ba[0];
    const float qdv = qdkd[(b*T + i)*16 + h];
    const int j1 = lane, j2 = 64 + lane;

    float e1s = part[0][h][j1] + part[1][h][j1] + part[2][h][j1] + part[3][h][j1];
    float e2s = part[0][h][j2] + part[1][h][j2] + part[2][h][j2] + part[3][h][j2];
    float l1 = qdv + qdkd[(b*T + 1 + j1)*16 + 8 + h] + e1s + ecw + ba0;
    float l2 = qdv + qdkd[(b*T + 1 + j2)*16 + 8 + h] + e2s + ecw + ba0;
    if (i >= 1) {
        const float* prow = prior + ((size_t)(b*H + h)*S + (i-1))*S;
        const float p1 = fminf(fmaxf(prow[j1], 1e-6f), 1.f - 1e-6f);
        const float p2 = fminf(fmaxf(prow[j2], 1e-6f), 1.f - 1e-6f);
        l1 += __logf(p1) - __logf(1.f - p1);
        l2 += __logf(p2) - __logf(1.f - p2);
        if (j1 == i - 1) l1 = NEG_INF;
        if (j2 == i - 1) l2 = NEG_INF;
    }

    float m = fmaxf(l1, l2);
    #pragma unroll
    for (int mm = 32; mm >= 1; mm >>= 1) m = fmaxf(m, __shfl_xor(m, mm));
    const float e1 = __expf(l1 - m);
    const float e2 = __expf(l2 - m);
    float s = e1 + e2;
    #pragma unroll
    for (int mm = 32; mm >= 1; mm >>= 1) s += __shfl_xor(s, mm);
    const float inv = 1.f / s;
    const float at1 = e1 * inv, at2 = e2 * inv;

    float* arow = out_attn + (size_t)((b*H + h)*T + i)*T;
    arow[1 + j1] = at1;
    arow[1 + j2] = at2;
    if (lane == 0) arow[0] = 0.f;
    pat[h][j1] = at1;
    pat[h][j2] = at2;
    __syncthreads();

    // ---- Phase C: ctx ----
    const int d = lane & 31, half = lane >> 5;
    float acc = 0.f;
    const float* vb = v + (size_t)(b*T)*D + h*HD + d;
    #pragma unroll 8
    for (int jj = 0; jj < 64; ++jj) {
        const int jc = half * 64 + jj;
        acc = fmaf(pat[h][jc], vb[(size_t)(1 + jc)*D], acc);
    }
    acc += __shfl_xor(acc, 32);
    if (lane < 32)
        out_basis[((size_t)(b*T + i)*H + h)*HD + d] = acc;
}

extern "C" void kernel_launch(void* const* d_in, const int* in_sizes, int n_in,
                              void* d_out, int out_size, void* d_ws, size_t ws_size,
                              hipStream_t stream) {
    const float* desc  = (const float*)d_in[0];
    const float* nv    = (const float*)d_in[1];
    const float* prior = (const float*)d_in[2];
    const float* Wq  = (const float*)d_in[3];
    const float* bq  = (const float*)d_in[4];
    const float* Wk  = (const float*)d_in[5];
    const float* bk  = (const float*)d_in[6];
    const float* Wv  = (const float*)d_in[7];
    const float* bv  = (const float*)d_in[8];
    const float* wa  = (const float*)d_in[9];
    const float* ba  = (const float*)d_in[10];
    const float* We1 = (const float*)d_in[11];
    const float* be1 = (const float*)d_in[12];
    const float* lng = (const float*)d_in[13];
    const float* lnb = (const float*)d_in[14];
    const float* We2 = (const float*)d_in[15];
    const float* be2 = (const float*)d_in[16];

    float* ws = (float*)d_ws;
    float* U    = ws; ws += B*S*D;
    float* Ut   = ws; ws += B*D*S;
    float* Vt   = ws; ws += B*D*S;
    float* v    = ws; ws += B*T*D;
    float* qdkd = ws; ws += B*T*16;
    float* W2ca = ws; ws += D*H;
    float* ec   = ws; ws += H;

    float* out_basis = (float*)d_out;
    float* out_attn  = out_basis + B*T*H*HD;

    gemm_all<<<dim3(836), 256, 0, stream>>>(nv, desc, Wq, bq, Wk, bk, Wv, bv,
                                            We1, be1, We2, be2, wa,
                                            v, U, Ut, Vt, qdkd, W2ca, ec);
    edge_attn<<<dim3(B*T), 512, 0, stream>>>(U, Ut, Vt, W2ca, ec, lng, lnb,
                                             qdkd, prior, v, ba,
                                             out_basis, out_attn);
}